// Round 3
// baseline (89.615 us; speedup 1.0000x reference)
//
#include <hip/hip_runtime.h>
#include <math.h>
#include <float.h>

// ChamferLoss: set1/set2 [8, 4096, 3] fp32 -> scalar
// out = sum over both directions of per-point min distances / (8*4096*4096)
//
// d^2 = ||q||^2 + (||p||^2 - 2 q.p); points staged in LDS as {x,y,z,||p||^2}
// (one ds_read_b128 per point), ||q||^2 folded in after the min.
// QPT=8 queries per thread so 4 LDS point-reads amortize over 32 pairs.

#define BATCH   8
#define NPTS    4096
#define THREADS 1024
#define QB      256          // queries per block
#define QPT     8            // queries per thread
#define NGRP    32           // scan groups of 32 lanes (t>>5)
#define PPG     (NPTS/NGRP)  // 128 points scanned per group

__global__ __launch_bounds__(THREADS, 4)
void chamfer_main(const float* __restrict__ set1,
                  const float* __restrict__ set2,
                  float* __restrict__ out)
{
    __shared__ float4 dbp[NPTS];          // 64 KB: {x,y,z,||p||^2} per point
    __shared__ float  part[NGRP / 2][QB]; // 16 KB: per-wave-combined partial mins

    const int blk = blockIdx.x;           // 0..255
    const int dir = blk >> 7;             // 0: set1->set2, 1: set2->set1
    const int rem = blk & 127;
    const int b   = rem >> 4;             // batch 0..7
    const int qb  = rem & 15;             // query block 0..15

    const float* __restrict__ Q  = dir ? set2 : set1;
    const float* __restrict__ DB = dir ? set1 : set2;
    const float* __restrict__ DBb = DB + (size_t)b * NPTS * 3;

    const int t = threadIdx.x;

    // --- stage DB batch into LDS with precomputed ||p||^2 ---
    // 4096 points = 3072 float4 of raw xyz; thread t handles points 4t..4t+3
    {
        const float4* g4 = (const float4*)DBb;
        const float4 r0 = g4[3 * t + 0];
        const float4 r1 = g4[3 * t + 1];
        const float4 r2 = g4[3 * t + 2];
        // p0=(r0.x,r0.y,r0.z) p1=(r0.w,r1.x,r1.y) p2=(r1.z,r1.w,r2.x) p3=(r2.y,r2.z,r2.w)
        dbp[4 * t + 0] = make_float4(r0.x, r0.y, r0.z,
                                     fmaf(r0.x, r0.x, fmaf(r0.y, r0.y, r0.z * r0.z)));
        dbp[4 * t + 1] = make_float4(r0.w, r1.x, r1.y,
                                     fmaf(r0.w, r0.w, fmaf(r1.x, r1.x, r1.y * r1.y)));
        dbp[4 * t + 2] = make_float4(r1.z, r1.w, r2.x,
                                     fmaf(r1.z, r1.z, fmaf(r1.w, r1.w, r2.x * r2.x)));
        dbp[4 * t + 3] = make_float4(r2.y, r2.z, r2.w,
                                     fmaf(r2.y, r2.y, fmaf(r2.z, r2.z, r2.w * r2.w)));
    }

    // --- this thread's 8 query coefficient sets (-2*q) ---
    const int l = t & 31;                 // lane-in-group
    const int g = t >> 5;                 // scan group 0..31
    const int qbase = qb * QB;

    float qa[QPT], qbc[QPT], qc[QPT], dmin[QPT];
    #pragma unroll
    for (int j = 0; j < QPT; ++j) {
        const float* qp = Q + ((size_t)b * NPTS + qbase + l + 32 * j) * 3;
        qa[j]  = -2.0f * qp[0];
        qbc[j] = -2.0f * qp[1];
        qc[j]  = -2.0f * qp[2];
        dmin[j] = FLT_MAX;
    }

    __syncthreads();

    // --- scan this group's 128 points for 8 queries ---
    const float4* __restrict__ s4 = dbp + g * PPG;

    #pragma unroll 2
    for (int c = 0; c < PPG / 4; ++c) {
        const float4 P0 = s4[c * 4 + 0];
        const float4 P1 = s4[c * 4 + 1];
        const float4 P2 = s4[c * 4 + 2];
        const float4 P3 = s4[c * 4 + 3];
        #pragma unroll
        for (int j = 0; j < QPT; ++j) {
            const float a = qa[j], bb = qbc[j], cc = qc[j];
            float d0 = fmaf(a, P0.x, fmaf(bb, P0.y, fmaf(cc, P0.z, P0.w)));
            float d1 = fmaf(a, P1.x, fmaf(bb, P1.y, fmaf(cc, P1.z, P1.w)));
            float d2 = fmaf(a, P2.x, fmaf(bb, P2.y, fmaf(cc, P2.z, P2.w)));
            float d3 = fmaf(a, P3.x, fmaf(bb, P3.y, fmaf(cc, P3.z, P3.w)));
            // min3-friendly tree
            dmin[j] = fminf(fminf(fminf(d0, d1), d2), fminf(fminf(d3, dmin[j]), dmin[j]));
        }
    }

    // --- combine the two groups within each wave (same queries, lanes l and l+32) ---
    const int w = t >> 6;                 // wave 0..15
    #pragma unroll
    for (int j = 0; j < QPT; ++j) {
        const float other = __shfl_down(dmin[j], 32);
        if (l == (t & 63))                // lanes 0..31 of the wave
            part[w][l + 32 * j] = fminf(dmin[j], other);
    }
    __syncthreads();

    // --- combine waves, finish d = sqrt(max(q^2 + m, 0)), reduce sum ---
    if (t < QB) {                         // waves 0..3, fully active
        float m = part[0][t];
        #pragma unroll
        for (int ww = 1; ww < NGRP / 2; ++ww)
            m = fminf(m, part[ww][t]);
        const float* qp = Q + ((size_t)b * NPTS + qbase + t) * 3;
        const float qx = qp[0], qy = qp[1], qz = qp[2];
        const float q2 = fmaf(qx, qx, fmaf(qy, qy, qz * qz));
        float dist = sqrtf(fmaxf(q2 + m, 0.0f));

        #pragma unroll
        for (int off = 32; off > 0; off >>= 1)
            dist += __shfl_down(dist, off);
        if ((t & 63) == 0)
            atomicAdd(out, dist * (1.0f / 134217728.0f));  // 1/(8*4096*4096), exact 2^-27
    }
}

extern "C" void kernel_launch(void* const* d_in, const int* in_sizes, int n_in,
                              void* d_out, int out_size, void* d_ws, size_t ws_size,
                              hipStream_t stream) {
    const float* s1 = (const float*)d_in[0];
    const float* s2 = (const float*)d_in[1];
    float* out = (float*)d_out;

    hipMemsetAsync(out, 0, sizeof(float), stream);  // d_out poisoned 0xAA each call
    chamfer_main<<<dim3(256), dim3(THREADS), 0, stream>>>(s1, s2, out);
}